// Round 28
// baseline (912.777 us; speedup 1.0000x reference)
//
#include <hip/hip_runtime.h>
#include <math.h>

#define TT      4608   // tokens per stream (B*N)
#define BB      8
#define NTOK    576
#define CDIM    256
#define NHEADS  8
#define HIDDIM  1024

typedef __attribute__((ext_vector_type(8))) short bf8s;   // 8 bf16
typedef __attribute__((ext_vector_type(4))) float f4;
typedef __attribute__((ext_vector_type(4))) short sv4;
typedef __attribute__((ext_vector_type(8))) short sv8;

__device__ __forceinline__ f4 mfma16(bf8s a, bf8s b, f4 c) {
    return __builtin_amdgcn_mfma_f32_16x16x32_bf16(a, b, c, 0, 0, 0);
}

__device__ __forceinline__ unsigned short f2bf(float x) {
    union { float f; unsigned int u; } v; v.f = x;
    unsigned int r = v.u + 0x7FFFu + ((v.u >> 16) & 1u);
    return (unsigned short)(r >> 16);
}
__device__ __forceinline__ float bf2f(unsigned short h) {
    union { unsigned int u; float f; } v; v.u = ((unsigned int)h) << 16;
    return v.f;
}
// HW packed f32->bf16 (RNE)
__device__ __forceinline__ unsigned int cvtpk(float a, float b) {
    unsigned int r;
    asm("v_cvt_pk_bf16_f32 %0, %1, %2" : "=v"(r) : "v"(a), "v"(b));
    return r;
}

__device__ __forceinline__ float gelu_f(float x) {
    return 0.5f * x * (1.0f + erff(x * 0.70710678118654752f));
}

// Fast normalized RBF bases: e_g ∝ exp(g*t - 2g^2), t = 10v+10; one exp + recurrence.
// v clamped to ±1.6 (sub-bf16 effect); reference's +1e-8 saturation via fade term g.
__device__ __forceinline__ void bases6(float v, float* out) {
    float vc = fminf(fmaxf(v, -1.6f), 1.6f);
    float t = fmaf(vc, 10.f, 10.f);
    float r = __expf(t);
    float e0 = 1.f;
    float e1 = r * 1.3533528e-1f;
    float e2 = e1 * (r * 2.4787522e-3f);
    float e3 = e2 * (r * 4.5399930e-5f);
    float e4 = e3 * (r * 8.3152872e-7f);
    float e5 = e4 * (r * 1.5229979e-8f);
    float av = fmaxf(fabsf(v) - 1.f, 0.f);
    float g = __expf(fminf(fmaf(av * av, 12.5f, -18.420681f), 80.f));
    float inv = 1.f / ((e0 + e1 + e2 + e3 + e4 + e5) * (1.f + g));
    out[0] = e0 * inv; out[1] = e1 * inv; out[2] = e2 * inv;
    out[3] = e3 * inv; out[4] = e4 * inv; out[5] = e5 * inv;
}

// groups-of-8 pack (w2 fused-expand path)
__device__ __forceinline__ int4 expand_pack(float v) {
    float b6[6]; bases6(v, b6);
    int4 pk;
    pk.x = (int)cvtpk(v, b6[0]);
    pk.y = (int)cvtpk(b6[1], b6[2]);
    pk.z = (int)cvtpk(b6[3], b6[4]);
    pk.w = (int)cvtpk(b6[5], 0.f);
    return pk;
}

// concatenated-layout single-value store: x at row+col, bases (12B, 4B-aligned) at row+256+col*6
__device__ __forceinline__ void expand_cat1(float v, unsigned short* rowp, int col) {
    rowp[col] = f2bf(v);
    float b6[6]; bases6(v, b6);
    int* ip = (int*)(rowp + 256 + (size_t)col * 6);
    ip[0] = (int)cvtpk(b6[0], b6[1]);
    ip[1] = (int)cvtpk(b6[2], b6[3]);
    ip[2] = (int)cvtpk(b6[4], b6[5]);
}

__device__ __forceinline__ void gload16(const void* g, void* l) {
    __builtin_amdgcn_global_load_lds(
        (const __attribute__((address_space(1))) unsigned int*)g,
        (__attribute__((address_space(3))) unsigned int*)l, 16, 0, 0);
}

// ---------------- transpose BOTH streams (B,C,H,W) -> (T, C) fp32, one launch
// (+opt fused l=0 QKV expansion into AEXP; X store skipped then -- dead until l=2) ----------------
__global__ __launch_bounds__(256) void k_transpose2(const float* __restrict__ inA,
                                                    const float* __restrict__ inB,
                                                    float* __restrict__ out,
                                                    unsigned short* __restrict__ aexp,
                                                    int doExp) {
    int idx = blockIdx.x * 256 + threadIdx.x;
    if (idx >= 2 * TT * CDIM) return;
    int s = idx >= TT * CDIM;
    int off = idx - s * TT * CDIM;
    const float* in = s ? inB : inA;
    int t = off >> 8, c = off & 255;
    int b = t / NTOK, n = t % NTOK;
    float v = in[(b * CDIM + c) * NTOK + n];
    if (doExp) expand_cat1(v, aexp + (size_t)(idx >> 8) * 1792, c);
    else out[idx] = v;
}

// ---------------- reduce S bf16 partial slices -> f32 ----------------
__global__ __launch_bounds__(256) void k_reduceS(const unsigned short* __restrict__ p,
                                                 float4* __restrict__ out, int n4, int S) {
    int i = blockIdx.x * 256 + threadIdx.x;
    if (i >= n4) return;
    float a0 = 0.f, a1 = 0.f, a2 = 0.f, a3 = 0.f;
    for (int s = 0; s < S; s++) {
        sv4 v = *(const sv4*)(p + (size_t)s * n4 * 4 + (size_t)i * 4);
        a0 += bf2f((unsigned short)v[0]); a1 += bf2f((unsigned short)v[1]);
        a2 += bf2f((unsigned short)v[2]); a3 += bf2f((unsigned short)v[3]);
    }
    out[i] = make_float4(a0, a1, a2, a3);
}

// ---------------- reduce S bf16 partials -> SEb f32 AND concatenated AEXP (K=1792) ----------
__global__ __launch_bounds__(256) void k_reduce_exp(const unsigned short* __restrict__ p,
                                                    float4* __restrict__ seb,
                                                    unsigned short* __restrict__ aexp,
                                                    int n4, int S) {
    int i = blockIdx.x * 256 + threadIdx.x;
    if (i >= n4) return;
    float a0 = 0.f, a1 = 0.f, a2 = 0.f, a3 = 0.f;
    for (int s = 0; s < S; s++) {
        sv4 v = *(const sv4*)(p + (size_t)s * n4 * 4 + (size_t)i * 4);
        a0 += bf2f((unsigned short)v[0]); a1 += bf2f((unsigned short)v[1]);
        a2 += bf2f((unsigned short)v[2]); a3 += bf2f((unsigned short)v[3]);
    }
    seb[i] = make_float4(a0, a1, a2, a3);
    int t = i >> 6, i4 = (i & 63) << 2;
    float xa[4] = {a0, a1, a2, a3};
    unsigned short* rowp = aexp + (size_t)t * 1792;
    sv4 xs;
    unsigned short tmp[24];
#pragma unroll
    for (int u = 0; u < 4; u++) {
        xs[u] = (short)f2bf(xa[u]);
        float b6[6]; bases6(xa[u], b6);
#pragma unroll
        for (int g = 0; g < 6; g++) tmp[u * 6 + g] = f2bf(b6[g]);
    }
    *(sv4*)(rowp + i4) = xs;
    sv8* bp = (sv8*)(rowp + 256 + (size_t)i4 * 6);
#pragma unroll
    for (int k = 0; k < 3; k++) bp[k] = *(sv8*)&tmp[k * 8];
}

// ---------------- expand fp32 (Mr,256) -> concatenated bf16 [x|bases] (Mr,1792) ----------
__global__ __launch_bounds__(256) void k_expand8(const float* __restrict__ x,
                                                 unsigned short* __restrict__ out, int Mr) {
    int idx = blockIdx.x * 256 + threadIdx.x;
    if (idx >= Mr * 64) return;
    int t = idx >> 6, i4 = (idx & 63) << 2;
    float4 xv = *(const float4*)(x + (size_t)t * 256 + i4);
    float xa[4] = {xv.x, xv.y, xv.z, xv.w};
    unsigned short* rowp = out + (size_t)t * 1792;
    sv4 xs;
    unsigned short tmp[24];
#pragma unroll
    for (int u = 0; u < 4; u++) {
        xs[u] = (short)f2bf(xa[u]);
        float b6[6]; bases6(xa[u], b6);
#pragma unroll
        for (int g = 0; g < 6; g++) tmp[u * 6 + g] = f2bf(b6[g]);
    }
    *(sv4*)(rowp + i4) = xs;
    sv8* bp = (sv8*)(rowp + 256 + (size_t)i4 * 6);
#pragma unroll
    for (int k = 0; k < 3; k++) bp[k] = *(sv8*)&tmp[k * 8];
}

// ---------------- pack weights (layer = blockIdx.y) ----------
// Wq/Wp/Ww1: concatenated [base(256)|spline(1536)] K=1792. Ww2: groups-of-8 K=8192.
__global__ __launch_bounds__(256) void k_pack8(
    const float* __restrict__ sqb, const float* __restrict__ sqs,
    const float* __restrict__ uqb, const float* __restrict__ uqs,
    const float* __restrict__ w1b, const float* __restrict__ w1s,
    const float* __restrict__ w2b, const float* __restrict__ w2s,
    unsigned short* __restrict__ Wq, unsigned short* __restrict__ Wp,
    unsigned short* __restrict__ Ww1, unsigned short* __restrict__ Ww2) {
    const size_t B1 = 688128, B2 = 917504, B3 = 1376256;   // thread boundaries
    const int ly = blockIdx.y;
    const size_t bofs = (size_t)ly * 262144, sofs = (size_t)ly * 1572864;
    size_t idx = (size_t)blockIdx.x * 256 + threadIdx.x;    // total 1638400
    if (idx < B3) {
        const float* base; const float* spl; unsigned short* dst; size_t e;
        if (idx < B1) {
            e = idx * 4;
            int s = e >= 1376256; size_t off = e - (size_t)s * 1376256;
            int r = (int)(off / 1792), c = (int)(off % 1792);
            base = (s ? uqb : sqb) + bofs + (size_t)r * 256;
            spl  = (s ? uqs : sqs) + sofs + (size_t)r * 1536;
            dst = Wq + (size_t)ly * 2752512 + e;
            float4 v = (c < 256) ? *(const float4*)(base + c)
                                 : *(const float4*)(spl + (c - 256));
            int2 pk; pk.x = (int)cvtpk(v.x, v.y); pk.y = (int)cvtpk(v.z, v.w);
            *(int2*)dst = pk;
        } else if (idx < B2) {
            e = (idx - B1) * 4;
            int s = e >= 458752; size_t off = e - (size_t)s * 458752;
            int r = (int)(off / 1792), c = (int)(off % 1792);
            base = (s ? uqb : sqb) + bofs + 3 * 65536 + (size_t)r * 256;
            spl  = (s ? uqs : sqs) + sofs + 3 * 393216 + (size_t)r * 1536;
            dst = Wp + (size_t)ly * 917504 + e;
            float4 v = (c < 256) ? *(const float4*)(base + c)
                                 : *(const float4*)(spl + (c - 256));
            int2 pk; pk.x = (int)cvtpk(v.x, v.y); pk.y = (int)cvtpk(v.z, v.w);
            *(int2*)dst = pk;
        } else {
            e = (idx - B2) * 4;
            int r = (int)(e / 1792), c = (int)(e % 1792);
            base = w1b + bofs + (size_t)r * 256;
            spl  = w1s + sofs + (size_t)r * 1536;
            dst = Ww1 + (size_t)ly * 1835008 + e;
            float4 v = (c < 256) ? *(const float4*)(base + c)
                                 : *(const float4*)(spl + (c - 256));
            int2 pk; pk.x = (int)cvtpk(v.x, v.y); pk.y = (int)cvtpk(v.z, v.w);
            *(int2*)dst = pk;
        }
    } else {
        size_t g = idx - B3;                    // 0..262143
        const float* base = w2b + bofs;
        const float* spl  = w2s + sofs;
        unsigned short* dst = Ww2 + (size_t)ly * 2097152 + g * 8;
        float bv = base[g];
        float2 s01 = *(const float2*)(spl + g * 6);
        float2 s23 = *(const float2*)(spl + g * 6 + 2);
        float2 s45 = *(const float2*)(spl + g * 6 + 4);
        int4 pk;
        pk.x = (int)cvtpk(bv, s01.x);
        pk.y = (int)cvtpk(s01.y, s23.x);
        pk.z = (int)cvtpk(s23.y, s45.x);
        pk.w = (int)cvtpk(s45.y, 0.f);
        *(int4*)dst = pk;
    }
}

// ---------------- bf16 MFMA GEMM: swizzled LDS, dbuf, split-K, opt fused expand ----
// EXP 0: A bf16 (M,ALD) via global_load_lds. EXP 2: A raw bf16, groups-of-8 expand,
//        A-loads prefetched 4 K-steps ahead (register ring).
// CMODE: 0 = f32 partial at +sk*skStride, 2 = bf16, 5 = bf16 partial at +sk*skStride.
template<int BM, int BN, int ACT, int CMODE, int EXP>
__global__ __launch_bounds__(256) void mgemm(const void* __restrict__ Araw,
                                             const unsigned short* __restrict__ W0,
                                             const unsigned short* __restrict__ W1,
                                             void* __restrict__ Cv, int NN, int K,
                                             int ALD, int WLD, int gx, int groupRows,
                                             int S, int Kc, size_t skStride) {
    constexpr int MF = BM / 32;
    constexpr int NF = BN / 32;
    constexpr int PD = 4;   // A-prefetch depth (EXP!=0)
    __shared__ unsigned short As[2][BM * 32];
    __shared__ unsigned short Bs[2][BN * 32];
    int nwg = gridDim.x, orig = blockIdx.x;
    int q = nwg >> 3, r = nwg & 7;
    int xcd = orig & 7, loc = orig >> 3;
    int wg = (xcd < r ? xcd * (q + 1) : r * (q + 1) + (xcd - r) * q) + loc;
    int sk = wg % S; int rest = wg / S;
    int bx = rest % gx, by = rest / gx;
    const int bm = by * BM, bn = bx * BN;
    const unsigned short* W = (bm >= groupRows) ? W1 : W0;
    const int tid = threadIdx.x, l = tid & 63, w = tid >> 6;
    const int wr = w >> 1, wc = w & 1;
    const int sr = l >> 2;
    const int scg = (l & 3) ^ ((l >> 3) & 3);
    const int sc8 = scg * 8;
    const int fro = (l & 15) * 32 + (((l >> 4) ^ ((l >> 1) & 3)) << 3);
    const int k0 = sk * Kc;
    f4 acc[MF][NF];
#pragma unroll
    for (int m = 0; m < MF; m++)
#pragma unroll
        for (int n = 0; n < NF; n++) acc[m][n] = (f4){0.f, 0.f, 0.f, 0.f};

    const unsigned short* Abf = (const unsigned short*)Araw;
    float xvr[PD][BM / 64];
    auto loadXd = [&](int kt, int slot) {
#pragma unroll
        for (int it = 0; it < BM / 64; it++) {
            int ch = it * 4 + w;
            int row = bm + ch * 16 + sr;
            int xi = (kt >> 3) + scg;
            xvr[slot][it] = bf2f(Abf[(size_t)row * ALD + xi]);
        }
    };
    auto writeA = [&](int buf, int slot) {
#pragma unroll
        for (int it = 0; it < BM / 64; it++) {
            int ch = it * 4 + w;
            int4 pk = expand_pack(xvr[slot][it]);
            *(int4*)&As[buf][ch * 512 + l * 8] = pk;
        }
    };
    auto stageA = [&](int buf, int kt) {
#pragma unroll
        for (int it = 0; it < BM / 64; it++) {
            int ch = it * 4 + w;
            gload16(Abf + (size_t)(bm + ch * 16 + sr) * ALD + kt + sc8,
                    (void*)(&As[buf][ch * 512 + l * 8]));
        }
    };
    auto stageB = [&](int buf, int kt) {
#pragma unroll
        for (int it = 0; it < BN / 64; it++) {
            int ch = it * 4 + w;
            gload16(W + (size_t)(bn + ch * 16 + sr) * WLD + kt + sc8,
                    (void*)(&Bs[buf][ch * 512 + l * 8]));
        }
    };

    const int nt = Kc / 32;
    if constexpr (EXP == 0) {
        stageA(0, k0);
    } else {
        int npre = nt < PD ? nt : PD;
        for (int d = 0; d < npre; d++) loadXd(k0 + d * 32, d);
        writeA(0, 0);
    }
    stageB(0, k0);
    __syncthreads();
    for (int t = 0; t < nt; t++) {
        int cur = t & 1;
        if (t + 1 < nt) {
            if constexpr (EXP == 0) stageA(cur ^ 1, k0 + (t + 1) * 32);
            stageB(cur ^ 1, k0 + (t + 1) * 32);
        }
        if constexpr (EXP != 0) {
            if (t + PD < nt) loadXd(k0 + (t + PD) * 32, (t + PD) & (PD - 1));
        }
        bf8s af[MF], bfr[NF];
#pragma unroll
        for (int m = 0; m < MF; m++)
            af[m] = *(const bf8s*)&As[cur][(wr * MF + m) * 512 + fro];
#pragma unroll
        for (int n = 0; n < NF; n++)
            bfr[n] = *(const bf8s*)&Bs[cur][(wc * NF + n) * 512 + fro];
#pragma unroll
        for (int m = 0; m < MF; m++)
#pragma unroll
            for (int n = 0; n < NF; n++)
                acc[m][n] = mfma16(af[m], bfr[n], acc[m][n]);
        if constexpr (EXP != 0) { if (t + 1 < nt) writeA(cur ^ 1, (t + 1) & (PD - 1)); }
        __syncthreads();
    }
#pragma unroll
    for (int m = 0; m < MF; m++)
#pragma unroll
        for (int n = 0; n < NF; n++)
#pragma unroll
            for (int j = 0; j < 4; j++) {
                int row = bm + wr * (BM / 2) + m * 16 + (l >> 4) * 4 + j;
                int col = bn + wc * (BN / 2) + n * 16 + (l & 15);
                float v = acc[m][n][j];
                if (ACT == 1) v = gelu_f(v);
                size_t o = (size_t)row * NN + col;
                if (CMODE == 0)      ((float*)Cv)[(size_t)sk * skStride + o] = v;
                else if (CMODE == 5) ((unsigned short*)Cv)[(size_t)sk * skStride + o] = f2bf(v);
                else                 ((unsigned short*)Cv)[o] = f2bf(v);
            }
}

// ---------------- V transpose: QKV (z*576+n, 512+h*32+d) -> VT[((z*8+h)*32+d)*576+n] ----------------
__global__ __launch_bounds__(256) void k_vt(const unsigned short* __restrict__ QKV,
                                            unsigned short* __restrict__ VT) {
    const int n0 = blockIdx.x * 64, h = blockIdx.y, z = blockIdx.z;
    __shared__ unsigned short t[32][72];
    const int tid = threadIdx.x;
    {
        int nl = tid >> 2, d8 = (tid & 3) * 8;
        sv8 v = *(const sv8*)(QKV + ((size_t)z * 576 + n0 + nl) * 768 + 512 + h * 32 + d8);
#pragma unroll
        for (int j = 0; j < 8; j++) t[d8 + j][nl] = v[j];
    }
    __syncthreads();
    {
        int d = tid >> 3, n8 = (tid & 7) * 8;
        sv8 o;
#pragma unroll
        for (int j = 0; j < 8; j++) o[j] = t[d][n8 + j];
        *(sv8*)(VT + ((size_t)(z * 8 + h) * 32 + d) * 576 + n0 + n8) = o;
    }
}

// ---------------- MFMA flash attention; bias table computed in-kernel (same math as
// the former k_bias_tab -> bit-identical values); writes CONCATENATED proj-A (K=1792) ----
__global__ __launch_bounds__(256) void k_attn2(const unsigned short* __restrict__ QKV,
                                               const unsigned short* __restrict__ VT,
                                               const float* __restrict__ rb0,
                                               const float* __restrict__ rs0,
                                               const float* __restrict__ rb1,
                                               const float* __restrict__ rs1,
                                               unsigned short* __restrict__ AX) {
    int nwg = gridDim.x, orig = blockIdx.x;
    int qq = nwg >> 3, rr_ = nwg & 7;
    int xcd = orig & 7, loc = orig >> 3;
    int wg = (xcd < rr_ ? xcd * (qq + 1) : rr_ * (qq + 1) + (xcd - rr_) * qq) + loc;
    const int n0 = (wg % 18) * 32;
    const int h = (wg / 18) & 7;
    const int z = wg / 144;
    const int tid = threadIdx.x, l = tid & 63, w = tid >> 6;
    const int rh = (w & 1) * 16;
    const int kh = (w >> 1) * 16;
    __shared__ unsigned short Ps[4][32 * 40];
    __shared__ float red[4][16];
    __shared__ float bt[2209];
    const float scale = 0.17677669529663687f;
    const size_t rowbase = (size_t)z * NTOK;
    {
        const int sidx = z >> 3;
        const float* rb = sidx ? rb1 : rb0;
        const float* rs = sidx ? rs1 : rs0;
        for (int i = tid; i < 2209; i += 256) {
            float r0c = (float)(i / 47 - 23) * (1.0f / 23.0f);
            float r1c = (float)(i % 47 - 23) * (1.0f / 23.0f);
            float v0[6], v1[6];
            bases6(r0c, v0);
            bases6(r1c, v1);
            float sbt = rb[h * 2] * r0c + rb[h * 2 + 1] * r1c;
#pragma unroll
            for (int g = 0; g < 6; g++)
                sbt += rs[h * 12 + g] * v0[g] + rs[h * 12 + 6 + g] * v1[g];
            bt[i] = sbt;
        }
    }
    const unsigned short* VTh = VT + ((size_t)(z * 8 + h) * 32) * 576;

    bf8s qf = *(const bf8s*)(QKV + (rowbase + n0 + rh + (l & 15)) * 768 + h * 32 + (l >> 4) * 8);

    f4 s[18];
#pragma unroll
    for (int kc = 0; kc < 18; kc++) {
        bf8s kf = *(const bf8s*)(QKV + (rowbase + kc * 32 + kh + (l & 15)) * 768 + 256 + h * 32 + (l >> 4) * 8);
        f4 zz = {0.f, 0.f, 0.f, 0.f};
        s[kc] = mfma16(qf, kf, zz);
    }
    __syncthreads();   // bt ready

    const int r0 = n0 + rh + (l >> 4) * 4;
    int bidx[4];
#pragma unroll
    for (int j = 0; j < 4; j++) {
        int n = r0 + j;
        bidx[j] = (n / 24 + 23) * 47 + (n % 24 + 23);
    }
    int m0 = kh + (l & 15);
    int mq = (m0 >= 24) ? 1 : 0;
    int mr = m0 - 24 * mq;
    float mx[4] = {-1e30f, -1e30f, -1e30f, -1e30f};
#pragma unroll
    for (int kc = 0; kc < 18; kc++) {
        int moff = mq * 47 + mr;
        mr += 8; mq += 1;
        if (mr >= 24) { mr -= 24; mq += 1; }
#pragma unroll
        for (int j = 0; j < 4; j++) {
            float v = s[kc][j] * scale + bt[bidx[j] - moff];
            s[kc][j] = v;
            mx[j] = fmaxf(mx[j], v);
        }
    }
#pragma unroll
    for (int j = 0; j < 4; j++)
#pragma unroll
        for (int m = 1; m < 16; m <<= 1) mx[j] = fmaxf(mx[j], __shfl_xor(mx[j], m));
    if ((l & 15) == 0) {
#pragma unroll
        for (int j = 0; j < 4; j++) red[w][(l >> 4) * 4 + j] = mx[j];
    }
    __syncthreads();
#pragma unroll
    for (int j = 0; j < 4; j++) mx[j] = fmaxf(mx[j], red[w ^ 2][(l >> 4) * 4 + j]);
    __syncthreads();
    float sm[4] = {0.f, 0.f, 0.f, 0.f};
#pragma unroll
    for (int kc = 0; kc < 18; kc++)
#pragma unroll
        for (int j = 0; j < 4; j++) {
            float p = __expf(s[kc][j] - mx[j]);
            s[kc][j] = p;
            sm[j] += p;
        }
#pragma unroll
    for (int j = 0; j < 4; j++)
#pragma unroll
        for (int m = 1; m < 16; m <<= 1) sm[j] += __shfl_xor(sm[j], m);
    if ((l & 15) == 0) {
#pragma unroll
        for (int j = 0; j < 4; j++) red[w][(l >> 4) * 4 + j] = sm[j];
    }
    __syncthreads();
#pragma unroll
    for (int j = 0; j < 4; j++) sm[j] = 1.f / (sm[j] + red[w ^ 2][(l >> 4) * 4 + j]);

    f4 oacc = {0.f, 0.f, 0.f, 0.f};
#pragma unroll
    for (int kc2 = 0; kc2 < 18; kc2 += 2) {
        const int b0 = kc2 & 2;
#pragma unroll
        for (int u = 0; u < 2; u++) {
            int kc = kc2 + u;
#pragma unroll
            for (int j = 0; j < 4; j++)
                Ps[b0 + u][(rh + (l >> 4) * 4 + j) * 40 + kh + (l & 15)] = f2bf(s[kc][j]);
        }
        __syncthreads();
#pragma unroll
        for (int u = 0; u < 2; u++) {
            int kc = kc2 + u;
            bf8s pf = *(const bf8s*)&Ps[b0 + u][(rh + (l & 15)) * 40 + (l >> 4) * 8];
            bf8s vf = *(const bf8s*)(VTh + (size_t)(kh + (l & 15)) * 576 + kc * 32 + (l >> 4) * 8);
            oacc = mfma16(pf, vf, oacc);
        }
    }
#pragma unroll
    for (int j = 0; j < 4; j++) {
        float ov = oacc[j] * sm[j];
        size_t rowi = rowbase + n0 + rh + (l >> 4) * 4 + j;
        expand_cat1(ov, AX + rowi * 1792, h * 32 + kh + (l & 15));
    }
}

// ---------------- layernorm(sum of S bf16 partials) + residual;
// doExp: write next-layer AEXP expansion INSTEAD of X (X dead until last layer) ----
__global__ __launch_bounds__(256) void k_ln_addS(const unsigned short* __restrict__ P,
                                                 int S, size_t st,
                                                 const float* __restrict__ SE,
                                                 const float* __restrict__ g,
                                                 const float* __restrict__ bb,
                                                 float* __restrict__ Out,
                                                 unsigned short* __restrict__ aexp,
                                                 int doExp) {
    int t = blockIdx.x, c = threadIdx.x;
    size_t o = (size_t)t * 256 + c;
    float v = 0.f;
    for (int s = 0; s < S; s++) v += bf2f(P[o + (size_t)s * st]);
    float s1 = v, s2 = v * v;
#pragma unroll
    for (int off = 32; off; off >>= 1) { s1 += __shfl_xor(s1, off); s2 += __shfl_xor(s2, off); }
    __shared__ float p1[4], p2[4];
    int wv_ = c >> 6, ln = c & 63;
    if (ln == 0) { p1[wv_] = s1; p2[wv_] = s2; }
    __syncthreads();
    s1 = p1[0] + p1[1] + p1[2] + p1[3];
    s2 = p2[0] + p2[1] + p2[2] + p2[3];
    float m = s1 * (1.f / 256.f);
    float var = s2 * (1.f / 256.f) - m * m;
    float y = (v - m) * rsqrtf(var + 1e-5f) * g[c] + bb[c];
    float xn = SE[o] + y;
    if (doExp) expand_cat1(xn, aexp + (size_t)t * 1792, c);
    else Out[o] = xn;
}

__global__ __launch_bounds__(256) void k_ln_gelu(const float* __restrict__ Xin,
                                                 const float* __restrict__ g,
                                                 const float* __restrict__ bb,
                                                 float* __restrict__ Out) {
    int t = blockIdx.x, c = threadIdx.x;
    float v = Xin[t * 256 + c];
    float s1 = v, s2 = v * v;
#pragma unroll
    for (int off = 32; off; off >>= 1) { s1 += __shfl_xor(s1, off); s2 += __shfl_xor(s2, off); }
    __shared__ float p1[4], p2[4];
    int wv_ = c >> 6, ln = c & 63;
    if (ln == 0) { p1[wv_] = s1; p2[wv_] = s2; }
    __syncthreads();
    s1 = p1[0] + p1[1] + p1[2] + p1[3];
    s2 = p2[0] + p2[1] + p2[2] + p2[3];
    float m = s1 * (1.f / 256.f);
    float var = s2 * (1.f / 256.f) - m * m;
    float y = (v - m) * rsqrtf(var + 1e-5f) * g[c] + bb[c];
    Out[t * 256 + c] = gelu_f(y);
}

// ---------------- mean pool, BOTH streams in one launch ----------------
__global__ __launch_bounds__(256) void k_meanpool2(const float* __restrict__ X,
                                                   float* __restrict__ si) {
    int idx = blockIdx.x * 256 + threadIdx.x;
    if (idx >= 2 * BB * CDIM) return;
    int st = idx >= BB * CDIM;
    int off = idx - st * BB * CDIM;
    int b = off >> 8, c = off & 255;
    const float* Xs = X + (size_t)st * TT * 256;
    float s = 0.f;
    for (int n = 0; n < NTOK; n++) s += Xs[(size_t)(b * NTOK + n) * CDIM + c];
    si[b * 512 + st * 256 + c] = s * (1.f / 576.f);
}

// ---------------- head: KAN with inline bases expansion (+opt fusion-gate on input) ----
// Wb: (NN, K1) base weights. Ws: (NN, K1, 6) spline weights. gate: per-t scalar or null.
__global__ __launch_bounds__(64) void k_kan2(const float* __restrict__ A1, int K1,
                                             const float* __restrict__ Wb,
                                             const float* __restrict__ Ws,
                                             const float* __restrict__ gate,
                                             float* __restrict__ out, int NN, int act) {
    int o = blockIdx.x, t = blockIdx.y, ln = threadIdx.x;
    float s = 0.f;
    for (int k = ln; k < K1; k += 64) {
        float x = A1[t * K1 + k];
        if (gate) x *= (k < 256 ? gate[t] : 1.f - gate[t]);
        s += x * Wb[o * K1 + k];
        float b6[6]; bases6(x, b6);
        const float* wsp = Ws + ((size_t)o * K1 + k) * 6;
#pragma unroll
        for (int g = 0; g < 6; g++) s += b6[g] * wsp[g];
    }
#pragma unroll
    for (int off = 32; off; off >>= 1) s += __shfl_xor(s, off);
    if (ln == 0) {
        if (act == 1) s = gelu_f(s);
        else if (act == 2) s = 1.f / (1.f + __expf(-s));
        out[t * NN + o] = s;
    }
}

extern "C" void kernel_launch(void* const* d_in, const int* in_sizes, int n_in,
                              void* d_out, int out_size, void* d_ws, size_t ws_size,
                              hipStream_t stream) {
    (void)in_sizes; (void)n_in; (void)out_size;
    const float* sat_f = (const float*)d_in[0];
    const float* uav_f = (const float*)d_in[1];
    const float* s_qb  = (const float*)d_in[2];
    const float* s_qs  = (const float*)d_in[3];
    const float* s_rb  = (const float*)d_in[4];
    const float* s_rs  = (const float*)d_in[5];
    const float* u_qb  = (const float*)d_in[6];
    const float* u_qs  = (const float*)d_in[7];
    const float* u_rb  = (const float*)d_in[8];
    const float* u_rs  = (const float*)d_in[9];
    const float* r_w1b = (const float*)d_in[10];
    const float* r_w1s = (const float*)d_in[11];
    const float* r_w2b = (const float*)d_in[12];
    const float* r_w2s = (const float*)d_in[13];
    const float* r_lng = (const float*)d_in[14];
    const float* r_lnb = (const float*)d_in[15];
    const float* m_w1b = (const float*)d_in[16];
    const float* m_w1s = (const float*)d_in[17];
    const float* m_w2b = (const float*)d_in[18];
    const float* m_w2s = (const float*)d_in[19];
    const float* m_w3b = (const float*)d_in[20];
    const float* m_w3s = (const float*)d_in[21];
    const float* f_wb  = (const float*)d_in[22];
    const float* f_ws  = (const float*)d_in[23];
    const float* f_lng = (const float*)d_in[24];
    const float* f_lnb = (const float*)d_in[25];

    const size_t nQ = 1376256, nP = 458752;   // per-stream ushort counts (K=1792 layout)

    float* X; unsigned short* QKVb; unsigned short* VT; char* R; float* PS;
    unsigned short* AEXP;
    unsigned short *Wq, *Wp, *Ww1, *Ww2;
    float *Btab, *si, *SB, *h1f, *h2f, *wvv, *fiB, *ftmp;
    auto plan = [&](int nb, bool ded, bool pall, bool assign) -> size_t {
        size_t off = 0;
        auto take = [&](size_t bytes) -> char* {
            char* rp = (char*)d_ws + off;
            off = (off + bytes + 255) & ~(size_t)255;
            return rp;
        };
        size_t Mr = (size_t)nb * TT;
        int nl = pall ? 3 : 1;
        char* p;
        p = take((size_t)2 * TT * 256 * 4);             if (assign) X = (float*)p;
        p = take(Mr * 768 * 2);                         if (assign) QKVb = (unsigned short*)p;
        p = take(Mr * 256 * 2);                         if (assign) VT = (unsigned short*)p;
        p = take(Mr * 2048 * 2);                        if (assign) R = p;
        p = take((size_t)4 * Mr * 256 * 4);             if (assign) PS = (float*)p;
        if (ded) { p = take(Mr * 1792 * 2);             if (assign) AEXP = (unsigned short*)p; }
        else     { if (assign) AEXP = (unsigned short*)PS; }
        p = take((size_t)nl * 2 * nQ * 2);              if (assign) Wq = (unsigned short*)p;
        p = take((size_t)nl * 2 * nP * 2);              if (assign) Wp = (unsigned short*)p;
        p = take((size_t)nl * 1835008 * 2);             if (assign) Ww1 = (unsigned short*)p;
        p = take((size_t)nl * 2097152 * 2);             if (assign) Ww2 = (unsigned short*)p;
        p = take((size_t)nb * NHEADS * 2209 * 4);       if (assign) Btab = (float*)p;
        p = take(BB * 512 * 4);                         if (assign) si = (float*)p;
        p = take((size_t)BB * 1024 * 6 * 4);            if (assign) SB = (float*)p;
        p = take(BB * 1024 * 4);                        if (assign) h1f = (float*)p;
        p = take(BB * 64 * 4);                          if (assign) h2f = (float*)p;
        p = take(64 * 4);                               if (assign) wvv = (float*)p;
        p = take(BB * 512 * 4);                         if (assign) fiB = (float*)p;
        p = take(BB * 256 * 4);                         if (assign) ftmp = (float*)p;
        return off;
    };
    int nb; bool ded, pall;
    if      (ws_size >= plan(2, true,  true,  false)) { nb = 2; ded = true;  pall = true;  }
    else if (ws_size >= plan(2, true,  false, false)) { nb = 2; ded = true;  pall = false; }
    else if (ws_size >= plan(2, false, false, false)) { nb = 2; ded = false; pall = false; }
    else                                              { nb = 1; ded = true;  pall = false; }
    plan(nb, ded, pall, true);
    (void)Btab; (void)SB; (void)fiB;   // bias/bases now computed in-kernel; gate inline
    const bool fuseRed = ded;
    const bool fuseLn  = ded && (nb == 2);

    // transpose both streams; when fuseLn, emit l=0 QKV expansion directly and
    // skip the dead X store (X only read by final meanpool, written by l=2 ln_addS)
    k_transpose2<<<2 * TT, 256, 0, stream>>>(sat_f, uav_f, X, AEXP, fuseLn ? 1 : 0);

    const int Mr = nb * TT;
    const size_t pStride = (size_t)Mr * 256;
    unsigned short* AEXPp = (unsigned short*)R;    // attn-expanded proj input (K=1792 rows)
    unsigned short* H1bp  = (unsigned short*)R;
    float* SEbp = (float*)(R + (size_t)Mr * 1024 * 2);

    if (pall)
        k_pack8<<<dim3(6400, 3), 256, 0, stream>>>(s_qb, s_qs, u_qb, u_qs,
                                                   r_w1b, r_w1s, r_w2b, r_w2s,
                                                   Wq, Wp, Ww1, Ww2);

    for (int l = 0; l < 3; l++) {
        if (!pall)
            k_pack8<<<dim3(6400, 1), 256, 0, stream>>>(
                s_qb + (size_t)l * 262144, s_qs + (size_t)l * 1572864,
                u_qb + (size_t)l * 262144, u_qs + (size_t)l * 1572864,
                r_w1b + (size_t)l * 262144, r_w1s + (size_t)l * 1572864,
                r_w2b + (size_t)l * 262144, r_w2s + (size_t)l * 1572864,
                Wq, Wp, Ww1, Ww2);
        unsigned short* WqL  = Wq  + (pall ? (size_t)l * 2 * nQ : 0);
        unsigned short* WpL  = Wp  + (pall ? (size_t)l * 2 * nP : 0);
        unsigned short* Ww1L = Ww1 + (pall ? (size_t)l * 1835008 : 0);
        unsigned short* Ww2L = Ww2 + (pall ? (size_t)l * 2097152 : 0);

        for (int st0 = 0; st0 < 2; st0 += nb) {
            float* Xs = X + (size_t)st0 * TT * 256;
            const float* rbA = (st0 ? u_rb : s_rb) + l * 16;
            const float* rsA = (st0 ? u_rs : s_rs) + l * 96;
            // QKV: A = concatenated expanded X (K=1792); AEXP pre-filled by
            // transpose (l=0, fuseLn) or previous ln_addS (l>0, fuseLn)
            bool haveAexp = fuseLn;
            if (!haveAexp) k_expand8<<<Mr / 4, 256, 0, stream>>>(Xs, AEXP, Mr);
            mgemm<128, 128, 0, 2, 0><<<6 * (Mr / 128), 256, 0, stream>>>(
                AEXP, WqL + (size_t)st0 * nQ, WqL + nQ, (void*)QKVb,
                768, 1792, 1792, 1792, 6, TT, 1, 1792, 0);
            // V transpose + attention (bias computed in-kernel; writes concatenated proj-A)
            k_vt<<<dim3(9, 8, nb * 8), 256, 0, stream>>>(QKVb, VT);
            k_attn2<<<144 * nb * 8, 256, 0, stream>>>(QKVb, VT, rbA, rsA,
                                                      u_rb + l * 16, u_rs + l * 96, AEXPp);
            // proj: pure gload GEMM (K=1792), split-K S=4, bf16 partials; reduce (+w1 expand)
            mgemm<128, 128, 0, 5, 0><<<2 * (Mr / 128) * 4, 256, 0, stream>>>(
                AEXPp, WpL + (size_t)st0 * nP, WpL + nP, (void*)PS,
                256, 1792, 1792, 1792, 2, TT, 4, 448, pStride);
            if (fuseRed)
                k_reduce_exp<<<Mr / 4, 256, 0, stream>>>((const unsigned short*)PS, (float4*)SEbp, AEXP, Mr * 64, 4);
            else {
                k_reduceS<<<Mr / 4, 256, 0, stream>>>((const unsigned short*)PS, (float4*)SEbp, Mr * 64, 4);
                k_expand8<<<Mr / 4, 256, 0, stream>>>(SEbp, AEXP, Mr);
            }
            // refine w1: pure gload GEMM (K=1792, +gelu, bf16 out)
            mgemm<128, 128, 1, 2, 0><<<8 * (Mr / 128), 256, 0, stream>>>(
                AEXP, Ww1L, Ww1L, (void*)H1bp,
                1024, 1792, 1792, 1792, 8, TT, 1, 1792, 0);
            // refine w2: fused expand (groups-of-8 K=8192), BM=64 BN=256 gx=1, S=4,
            // bf16 partials -- best-known config
            mgemm<64, 256, 0, 5, 2><<<4 * (Mr / 64), 256, 0, stream>>>(
                H1bp, Ww2L, Ww2L, (void*)PS,
                256, 8192, 1024, 8192, 1, TT, 4, 2048, pStride);
            // LN(sum of 4 bf16 partials) + residual; l<2 fuseLn: write AEXP only
            // (X store dead); l=2 or fallback: write X
            k_ln_addS<<<Mr, 256, 0, stream>>>((const unsigned short*)PS, 4, pStride, SEbp,
                                              r_lng + l * 256, r_lnb + l * 256, Xs,
                                              AEXP, (fuseLn && l < 2) ? 1 : 0);
        }
    }

    // final head (fp32, tiny; inline bases expansion + inline fusion gate)
    k_meanpool2<<<16, 256, 0, stream>>>(X, si);
    k_kan2<<<dim3(1024, BB), 64, 0, stream>>>(si, 512, m_w1b, m_w1s, nullptr, h1f, 1024, 1);
    k_kan2<<<dim3(64, BB), 64, 0, stream>>>(h1f, 1024, m_w2b, m_w2s, nullptr, h2f, 64, 1);
    k_kan2<<<dim3(1, BB), 64, 0, stream>>>(h2f, 64, m_w3b, m_w3s, nullptr, wvv, 1, 2);
    k_kan2<<<dim3(256, BB), 64, 0, stream>>>(si, 512, f_wb, f_ws, wvv, ftmp, 256, 0);
    k_ln_gelu<<<8, 256, 0, stream>>>(ftmp, f_lng, f_lnb, (float*)d_out);
}

// Round 29
// 908.685 us; speedup vs baseline: 1.0045x; 1.0045x over previous
//
#include <hip/hip_runtime.h>
#include <math.h>

#define TT      4608   // tokens per stream (B*N)
#define BB      8
#define NTOK    576
#define CDIM    256
#define NHEADS  8
#define HIDDIM  1024

typedef __attribute__((ext_vector_type(8))) short bf8s;   // 8 bf16
typedef __attribute__((ext_vector_type(4))) float f4;
typedef __attribute__((ext_vector_type(4))) short sv4;
typedef __attribute__((ext_vector_type(8))) short sv8;

__device__ __forceinline__ f4 mfma16(bf8s a, bf8s b, f4 c) {
    return __builtin_amdgcn_mfma_f32_16x16x32_bf16(a, b, c, 0, 0, 0);
}

__device__ __forceinline__ unsigned short f2bf(float x) {
    union { float f; unsigned int u; } v; v.f = x;
    unsigned int r = v.u + 0x7FFFu + ((v.u >> 16) & 1u);
    return (unsigned short)(r >> 16);
}
__device__ __forceinline__ float bf2f(unsigned short h) {
    union { unsigned int u; float f; } v; v.u = ((unsigned int)h) << 16;
    return v.f;
}
// HW packed f32->bf16 (RNE)
__device__ __forceinline__ unsigned int cvtpk(float a, float b) {
    unsigned int r;
    asm("v_cvt_pk_bf16_f32 %0, %1, %2" : "=v"(r) : "v"(a), "v"(b));
    return r;
}

__device__ __forceinline__ float gelu_f(float x) {
    return 0.5f * x * (1.0f + erff(x * 0.70710678118654752f));
}

// Fast normalized RBF bases: e_g ∝ exp(g*t - 2g^2), t = 10v+10; one exp + recurrence.
// v clamped to ±1.6 (sub-bf16 effect); reference's +1e-8 saturation via fade term g.
__device__ __forceinline__ void bases6(float v, float* out) {
    float vc = fminf(fmaxf(v, -1.6f), 1.6f);
    float t = fmaf(vc, 10.f, 10.f);
    float r = __expf(t);
    float e0 = 1.f;
    float e1 = r * 1.3533528e-1f;
    float e2 = e1 * (r * 2.4787522e-3f);
    float e3 = e2 * (r * 4.5399930e-5f);
    float e4 = e3 * (r * 8.3152872e-7f);
    float e5 = e4 * (r * 1.5229979e-8f);
    float av = fmaxf(fabsf(v) - 1.f, 0.f);
    float g = __expf(fminf(fmaf(av * av, 12.5f, -18.420681f), 80.f));
    float inv = 1.f / ((e0 + e1 + e2 + e3 + e4 + e5) * (1.f + g));
    out[0] = e0 * inv; out[1] = e1 * inv; out[2] = e2 * inv;
    out[3] = e3 * inv; out[4] = e4 * inv; out[5] = e5 * inv;
}

// groups-of-8 pack (w2 fused-expand path)
__device__ __forceinline__ int4 expand_pack(float v) {
    float b6[6]; bases6(v, b6);
    int4 pk;
    pk.x = (int)cvtpk(v, b6[0]);
    pk.y = (int)cvtpk(b6[1], b6[2]);
    pk.z = (int)cvtpk(b6[3], b6[4]);
    pk.w = (int)cvtpk(b6[5], 0.f);
    return pk;
}

// concatenated-layout single-value store: x at row+col, bases (12B, 4B-aligned) at row+256+col*6
__device__ __forceinline__ void expand_cat1(float v, unsigned short* rowp, int col) {
    rowp[col] = f2bf(v);
    float b6[6]; bases6(v, b6);
    int* ip = (int*)(rowp + 256 + (size_t)col * 6);
    ip[0] = (int)cvtpk(b6[0], b6[1]);
    ip[1] = (int)cvtpk(b6[2], b6[3]);
    ip[2] = (int)cvtpk(b6[4], b6[5]);
}

__device__ __forceinline__ void gload16(const void* g, void* l) {
    __builtin_amdgcn_global_load_lds(
        (const __attribute__((address_space(1))) unsigned int*)g,
        (__attribute__((address_space(3))) unsigned int*)l, 16, 0, 0);
}

// ---------------- transpose BOTH streams (B,C,H,W) -> (T, C) fp32, one launch
// (+opt fused l=0 QKV expansion into AEXP; identical expand_cat1 math) ----------------
__global__ __launch_bounds__(256) void k_transpose2(const float* __restrict__ inA,
                                                    const float* __restrict__ inB,
                                                    float* __restrict__ out,
                                                    unsigned short* __restrict__ aexp,
                                                    int doExp) {
    int idx = blockIdx.x * 256 + threadIdx.x;
    if (idx >= 2 * TT * CDIM) return;
    int s = idx >= TT * CDIM;
    int off = idx - s * TT * CDIM;
    const float* in = s ? inB : inA;
    int t = off >> 8, c = off & 255;
    int b = t / NTOK, n = t % NTOK;
    float v = in[(b * CDIM + c) * NTOK + n];
    out[idx] = v;
    if (doExp) expand_cat1(v, aexp + (size_t)(idx >> 8) * 1792, c);
}

// ---------------- reduce S bf16 partial slices -> f32 ----------------
__global__ __launch_bounds__(256) void k_reduceS(const unsigned short* __restrict__ p,
                                                 float4* __restrict__ out, int n4, int S) {
    int i = blockIdx.x * 256 + threadIdx.x;
    if (i >= n4) return;
    float a0 = 0.f, a1 = 0.f, a2 = 0.f, a3 = 0.f;
    for (int s = 0; s < S; s++) {
        sv4 v = *(const sv4*)(p + (size_t)s * n4 * 4 + (size_t)i * 4);
        a0 += bf2f((unsigned short)v[0]); a1 += bf2f((unsigned short)v[1]);
        a2 += bf2f((unsigned short)v[2]); a3 += bf2f((unsigned short)v[3]);
    }
    out[i] = make_float4(a0, a1, a2, a3);
}

// ---------------- reduce S bf16 partials -> SEb f32 AND concatenated AEXP (K=1792) ----------
__global__ __launch_bounds__(256) void k_reduce_exp(const unsigned short* __restrict__ p,
                                                    float4* __restrict__ seb,
                                                    unsigned short* __restrict__ aexp,
                                                    int n4, int S) {
    int i = blockIdx.x * 256 + threadIdx.x;
    if (i >= n4) return;
    float a0 = 0.f, a1 = 0.f, a2 = 0.f, a3 = 0.f;
    for (int s = 0; s < S; s++) {
        sv4 v = *(const sv4*)(p + (size_t)s * n4 * 4 + (size_t)i * 4);
        a0 += bf2f((unsigned short)v[0]); a1 += bf2f((unsigned short)v[1]);
        a2 += bf2f((unsigned short)v[2]); a3 += bf2f((unsigned short)v[3]);
    }
    seb[i] = make_float4(a0, a1, a2, a3);
    int t = i >> 6, i4 = (i & 63) << 2;
    float xa[4] = {a0, a1, a2, a3};
    unsigned short* rowp = aexp + (size_t)t * 1792;
    sv4 xs;
    unsigned short tmp[24];
#pragma unroll
    for (int u = 0; u < 4; u++) {
        xs[u] = (short)f2bf(xa[u]);
        float b6[6]; bases6(xa[u], b6);
#pragma unroll
        for (int g = 0; g < 6; g++) tmp[u * 6 + g] = f2bf(b6[g]);
    }
    *(sv4*)(rowp + i4) = xs;
    sv8* bp = (sv8*)(rowp + 256 + (size_t)i4 * 6);
#pragma unroll
    for (int k = 0; k < 3; k++) bp[k] = *(sv8*)&tmp[k * 8];
}

// ---------------- expand fp32 (Mr,256) -> concatenated bf16 [x|bases] (Mr,1792) ----------
__global__ __launch_bounds__(256) void k_expand8(const float* __restrict__ x,
                                                 unsigned short* __restrict__ out, int Mr) {
    int idx = blockIdx.x * 256 + threadIdx.x;
    if (idx >= Mr * 64) return;
    int t = idx >> 6, i4 = (idx & 63) << 2;
    float4 xv = *(const float4*)(x + (size_t)t * 256 + i4);
    float xa[4] = {xv.x, xv.y, xv.z, xv.w};
    unsigned short* rowp = out + (size_t)t * 1792;
    sv4 xs;
    unsigned short tmp[24];
#pragma unroll
    for (int u = 0; u < 4; u++) {
        xs[u] = (short)f2bf(xa[u]);
        float b6[6]; bases6(xa[u], b6);
#pragma unroll
        for (int g = 0; g < 6; g++) tmp[u * 6 + g] = f2bf(b6[g]);
    }
    *(sv4*)(rowp + i4) = xs;
    sv8* bp = (sv8*)(rowp + 256 + (size_t)i4 * 6);
#pragma unroll
    for (int k = 0; k < 3; k++) bp[k] = *(sv8*)&tmp[k * 8];
}

// ---------------- pack weights (layer = blockIdx.y) ----------
// Wq/Wp/Ww1: concatenated [base(256)|spline(1536)] K=1792. Ww2: groups-of-8 K=8192.
__global__ __launch_bounds__(256) void k_pack8(
    const float* __restrict__ sqb, const float* __restrict__ sqs,
    const float* __restrict__ uqb, const float* __restrict__ uqs,
    const float* __restrict__ w1b, const float* __restrict__ w1s,
    const float* __restrict__ w2b, const float* __restrict__ w2s,
    unsigned short* __restrict__ Wq, unsigned short* __restrict__ Wp,
    unsigned short* __restrict__ Ww1, unsigned short* __restrict__ Ww2) {
    const size_t B1 = 688128, B2 = 917504, B3 = 1376256;   // thread boundaries
    const int ly = blockIdx.y;
    const size_t bofs = (size_t)ly * 262144, sofs = (size_t)ly * 1572864;
    size_t idx = (size_t)blockIdx.x * 256 + threadIdx.x;    // total 1638400
    if (idx < B3) {
        const float* base; const float* spl; unsigned short* dst; size_t e;
        if (idx < B1) {
            e = idx * 4;
            int s = e >= 1376256; size_t off = e - (size_t)s * 1376256;
            int r = (int)(off / 1792), c = (int)(off % 1792);
            base = (s ? uqb : sqb) + bofs + (size_t)r * 256;
            spl  = (s ? uqs : sqs) + sofs + (size_t)r * 1536;
            dst = Wq + (size_t)ly * 2752512 + e;
            float4 v = (c < 256) ? *(const float4*)(base + c)
                                 : *(const float4*)(spl + (c - 256));
            int2 pk; pk.x = (int)cvtpk(v.x, v.y); pk.y = (int)cvtpk(v.z, v.w);
            *(int2*)dst = pk;
        } else if (idx < B2) {
            e = (idx - B1) * 4;
            int s = e >= 458752; size_t off = e - (size_t)s * 458752;
            int r = (int)(off / 1792), c = (int)(off % 1792);
            base = (s ? uqb : sqb) + bofs + 3 * 65536 + (size_t)r * 256;
            spl  = (s ? uqs : sqs) + sofs + 3 * 393216 + (size_t)r * 1536;
            dst = Wp + (size_t)ly * 917504 + e;
            float4 v = (c < 256) ? *(const float4*)(base + c)
                                 : *(const float4*)(spl + (c - 256));
            int2 pk; pk.x = (int)cvtpk(v.x, v.y); pk.y = (int)cvtpk(v.z, v.w);
            *(int2*)dst = pk;
        } else {
            e = (idx - B2) * 4;
            int r = (int)(e / 1792), c = (int)(e % 1792);
            base = w1b + bofs + (size_t)r * 256;
            spl  = w1s + sofs + (size_t)r * 1536;
            dst = Ww1 + (size_t)ly * 1835008 + e;
            float4 v = (c < 256) ? *(const float4*)(base + c)
                                 : *(const float4*)(spl + (c - 256));
            int2 pk; pk.x = (int)cvtpk(v.x, v.y); pk.y = (int)cvtpk(v.z, v.w);
            *(int2*)dst = pk;
        }
    } else {
        size_t g = idx - B3;                    // 0..262143
        const float* base = w2b + bofs;
        const float* spl  = w2s + sofs;
        unsigned short* dst = Ww2 + (size_t)ly * 2097152 + g * 8;
        float bv = base[g];
        float2 s01 = *(const float2*)(spl + g * 6);
        float2 s23 = *(const float2*)(spl + g * 6 + 2);
        float2 s45 = *(const float2*)(spl + g * 6 + 4);
        int4 pk;
        pk.x = (int)cvtpk(bv, s01.x);
        pk.y = (int)cvtpk(s01.y, s23.x);
        pk.z = (int)cvtpk(s23.y, s45.x);
        pk.w = (int)cvtpk(s45.y, 0.f);
        *(int4*)dst = pk;
    }
}

// ---------------- bf16 MFMA GEMM: swizzled LDS, dbuf, split-K, opt fused expand ----
// EXP 0: A bf16 (M,ALD) via global_load_lds. EXP 2: A raw bf16, groups-of-8 expand,
//        A-loads prefetched 4 K-steps ahead (register ring).
// CMODE: 0 = f32 partial at +sk*skStride, 2 = bf16, 5 = bf16 partial at +sk*skStride.
template<int BM, int BN, int ACT, int CMODE, int EXP>
__global__ __launch_bounds__(256) void mgemm(const void* __restrict__ Araw,
                                             const unsigned short* __restrict__ W0,
                                             const unsigned short* __restrict__ W1,
                                             void* __restrict__ Cv, int NN, int K,
                                             int ALD, int WLD, int gx, int groupRows,
                                             int S, int Kc, size_t skStride) {
    constexpr int MF = BM / 32;
    constexpr int NF = BN / 32;
    constexpr int PD = 4;   // A-prefetch depth (EXP!=0)
    __shared__ unsigned short As[2][BM * 32];
    __shared__ unsigned short Bs[2][BN * 32];
    int nwg = gridDim.x, orig = blockIdx.x;
    int q = nwg >> 3, r = nwg & 7;
    int xcd = orig & 7, loc = orig >> 3;
    int wg = (xcd < r ? xcd * (q + 1) : r * (q + 1) + (xcd - r) * q) + loc;
    int sk = wg % S; int rest = wg / S;
    int bx = rest % gx, by = rest / gx;
    const int bm = by * BM, bn = bx * BN;
    const unsigned short* W = (bm >= groupRows) ? W1 : W0;
    const int tid = threadIdx.x, l = tid & 63, w = tid >> 6;
    const int wr = w >> 1, wc = w & 1;
    const int sr = l >> 2;
    const int scg = (l & 3) ^ ((l >> 3) & 3);
    const int sc8 = scg * 8;
    const int fro = (l & 15) * 32 + (((l >> 4) ^ ((l >> 1) & 3)) << 3);
    const int k0 = sk * Kc;
    f4 acc[MF][NF];
#pragma unroll
    for (int m = 0; m < MF; m++)
#pragma unroll
        for (int n = 0; n < NF; n++) acc[m][n] = (f4){0.f, 0.f, 0.f, 0.f};

    const unsigned short* Abf = (const unsigned short*)Araw;
    float xvr[PD][BM / 64];
    auto loadXd = [&](int kt, int slot) {
#pragma unroll
        for (int it = 0; it < BM / 64; it++) {
            int ch = it * 4 + w;
            int row = bm + ch * 16 + sr;
            int xi = (kt >> 3) + scg;
            xvr[slot][it] = bf2f(Abf[(size_t)row * ALD + xi]);
        }
    };
    auto writeA = [&](int buf, int slot) {
#pragma unroll
        for (int it = 0; it < BM / 64; it++) {
            int ch = it * 4 + w;
            int4 pk = expand_pack(xvr[slot][it]);
            *(int4*)&As[buf][ch * 512 + l * 8] = pk;
        }
    };
    auto stageA = [&](int buf, int kt) {
#pragma unroll
        for (int it = 0; it < BM / 64; it++) {
            int ch = it * 4 + w;
            gload16(Abf + (size_t)(bm + ch * 16 + sr) * ALD + kt + sc8,
                    (void*)(&As[buf][ch * 512 + l * 8]));
        }
    };
    auto stageB = [&](int buf, int kt) {
#pragma unroll
        for (int it = 0; it < BN / 64; it++) {
            int ch = it * 4 + w;
            gload16(W + (size_t)(bn + ch * 16 + sr) * WLD + kt + sc8,
                    (void*)(&Bs[buf][ch * 512 + l * 8]));
        }
    };

    const int nt = Kc / 32;
    if constexpr (EXP == 0) {
        stageA(0, k0);
    } else {
        int npre = nt < PD ? nt : PD;
        for (int d = 0; d < npre; d++) loadXd(k0 + d * 32, d);
        writeA(0, 0);
    }
    stageB(0, k0);
    __syncthreads();
    for (int t = 0; t < nt; t++) {
        int cur = t & 1;
        if (t + 1 < nt) {
            if constexpr (EXP == 0) stageA(cur ^ 1, k0 + (t + 1) * 32);
            stageB(cur ^ 1, k0 + (t + 1) * 32);
        }
        if constexpr (EXP != 0) {
            if (t + PD < nt) loadXd(k0 + (t + PD) * 32, (t + PD) & (PD - 1));
        }
        bf8s af[MF], bfr[NF];
#pragma unroll
        for (int m = 0; m < MF; m++)
            af[m] = *(const bf8s*)&As[cur][(wr * MF + m) * 512 + fro];
#pragma unroll
        for (int n = 0; n < NF; n++)
            bfr[n] = *(const bf8s*)&Bs[cur][(wc * NF + n) * 512 + fro];
#pragma unroll
        for (int m = 0; m < MF; m++)
#pragma unroll
            for (int n = 0; n < NF; n++)
                acc[m][n] = mfma16(af[m], bfr[n], acc[m][n]);
        if constexpr (EXP != 0) { if (t + 1 < nt) writeA(cur ^ 1, (t + 1) & (PD - 1)); }
        __syncthreads();
    }
#pragma unroll
    for (int m = 0; m < MF; m++)
#pragma unroll
        for (int n = 0; n < NF; n++)
#pragma unroll
            for (int j = 0; j < 4; j++) {
                int row = bm + wr * (BM / 2) + m * 16 + (l >> 4) * 4 + j;
                int col = bn + wc * (BN / 2) + n * 16 + (l & 15);
                float v = acc[m][n][j];
                if (ACT == 1) v = gelu_f(v);
                size_t o = (size_t)row * NN + col;
                if (CMODE == 0)      ((float*)Cv)[(size_t)sk * skStride + o] = v;
                else if (CMODE == 5) ((unsigned short*)Cv)[(size_t)sk * skStride + o] = f2bf(v);
                else                 ((unsigned short*)Cv)[o] = f2bf(v);
            }
}

// ---------------- V transpose: QKV (z*576+n, 512+h*32+d) -> VT[((z*8+h)*32+d)*576+n] ----------------
__global__ __launch_bounds__(256) void k_vt(const unsigned short* __restrict__ QKV,
                                            unsigned short* __restrict__ VT) {
    const int n0 = blockIdx.x * 64, h = blockIdx.y, z = blockIdx.z;
    __shared__ unsigned short t[32][72];
    const int tid = threadIdx.x;
    {
        int nl = tid >> 2, d8 = (tid & 3) * 8;
        sv8 v = *(const sv8*)(QKV + ((size_t)z * 576 + n0 + nl) * 768 + 512 + h * 32 + d8);
#pragma unroll
        for (int j = 0; j < 8; j++) t[d8 + j][nl] = v[j];
    }
    __syncthreads();
    {
        int d = tid >> 3, n8 = (tid & 7) * 8;
        sv8 o;
#pragma unroll
        for (int j = 0; j < 8; j++) o[j] = t[d][n8 + j];
        *(sv8*)(VT + ((size_t)(z * 8 + h) * 32 + d) * 576 + n0 + n8) = o;
    }
}

// ---------------- MFMA flash attention; bias table computed in-kernel (same math as
// the former k_bias_tab -> bit-identical values); writes CONCATENATED proj-A (K=1792) ----
__global__ __launch_bounds__(256) void k_attn2(const unsigned short* __restrict__ QKV,
                                               const unsigned short* __restrict__ VT,
                                               const float* __restrict__ rb0,
                                               const float* __restrict__ rs0,
                                               const float* __restrict__ rb1,
                                               const float* __restrict__ rs1,
                                               unsigned short* __restrict__ AX) {
    int nwg = gridDim.x, orig = blockIdx.x;
    int qq = nwg >> 3, rr_ = nwg & 7;
    int xcd = orig & 7, loc = orig >> 3;
    int wg = (xcd < rr_ ? xcd * (qq + 1) : rr_ * (qq + 1) + (xcd - rr_) * qq) + loc;
    const int n0 = (wg % 18) * 32;
    const int h = (wg / 18) & 7;
    const int z = wg / 144;
    const int tid = threadIdx.x, l = tid & 63, w = tid >> 6;
    const int rh = (w & 1) * 16;
    const int kh = (w >> 1) * 16;
    __shared__ unsigned short Ps[4][32 * 40];
    __shared__ float red[4][16];
    __shared__ float bt[2209];
    const float scale = 0.17677669529663687f;
    const size_t rowbase = (size_t)z * NTOK;
    {
        const int sidx = z >> 3;
        const float* rb = sidx ? rb1 : rb0;
        const float* rs = sidx ? rs1 : rs0;
        for (int i = tid; i < 2209; i += 256) {
            float r0c = (float)(i / 47 - 23) * (1.0f / 23.0f);
            float r1c = (float)(i % 47 - 23) * (1.0f / 23.0f);
            float v0[6], v1[6];
            bases6(r0c, v0);
            bases6(r1c, v1);
            float sbt = rb[h * 2] * r0c + rb[h * 2 + 1] * r1c;
#pragma unroll
            for (int g = 0; g < 6; g++)
                sbt += rs[h * 12 + g] * v0[g] + rs[h * 12 + 6 + g] * v1[g];
            bt[i] = sbt;
        }
    }
    const unsigned short* VTh = VT + ((size_t)(z * 8 + h) * 32) * 576;

    bf8s qf = *(const bf8s*)(QKV + (rowbase + n0 + rh + (l & 15)) * 768 + h * 32 + (l >> 4) * 8);

    f4 s[18];
#pragma unroll
    for (int kc = 0; kc < 18; kc++) {
        bf8s kf = *(const bf8s*)(QKV + (rowbase + kc * 32 + kh + (l & 15)) * 768 + 256 + h * 32 + (l >> 4) * 8);
        f4 zz = {0.f, 0.f, 0.f, 0.f};
        s[kc] = mfma16(qf, kf, zz);
    }
    __syncthreads();   // bt ready

    const int r0 = n0 + rh + (l >> 4) * 4;
    int bidx[4];
#pragma unroll
    for (int j = 0; j < 4; j++) {
        int n = r0 + j;
        bidx[j] = (n / 24 + 23) * 47 + (n % 24 + 23);
    }
    int m0 = kh + (l & 15);
    int mq = (m0 >= 24) ? 1 : 0;
    int mr = m0 - 24 * mq;
    float mx[4] = {-1e30f, -1e30f, -1e30f, -1e30f};
#pragma unroll
    for (int kc = 0; kc < 18; kc++) {
        int moff = mq * 47 + mr;
        mr += 8; mq += 1;
        if (mr >= 24) { mr -= 24; mq += 1; }
#pragma unroll
        for (int j = 0; j < 4; j++) {
            float v = s[kc][j] * scale + bt[bidx[j] - moff];
            s[kc][j] = v;
            mx[j] = fmaxf(mx[j], v);
        }
    }
#pragma unroll
    for (int j = 0; j < 4; j++)
#pragma unroll
        for (int m = 1; m < 16; m <<= 1) mx[j] = fmaxf(mx[j], __shfl_xor(mx[j], m));
    if ((l & 15) == 0) {
#pragma unroll
        for (int j = 0; j < 4; j++) red[w][(l >> 4) * 4 + j] = mx[j];
    }
    __syncthreads();
#pragma unroll
    for (int j = 0; j < 4; j++) mx[j] = fmaxf(mx[j], red[w ^ 2][(l >> 4) * 4 + j]);
    __syncthreads();
    float sm[4] = {0.f, 0.f, 0.f, 0.f};
#pragma unroll
    for (int kc = 0; kc < 18; kc++)
#pragma unroll
        for (int j = 0; j < 4; j++) {
            float p = __expf(s[kc][j] - mx[j]);
            s[kc][j] = p;
            sm[j] += p;
        }
#pragma unroll
    for (int j = 0; j < 4; j++)
#pragma unroll
        for (int m = 1; m < 16; m <<= 1) sm[j] += __shfl_xor(sm[j], m);
    if ((l & 15) == 0) {
#pragma unroll
        for (int j = 0; j < 4; j++) red[w][(l >> 4) * 4 + j] = sm[j];
    }
    __syncthreads();
#pragma unroll
    for (int j = 0; j < 4; j++) sm[j] = 1.f / (sm[j] + red[w ^ 2][(l >> 4) * 4 + j]);

    f4 oacc = {0.f, 0.f, 0.f, 0.f};
#pragma unroll
    for (int kc2 = 0; kc2 < 18; kc2 += 2) {
        const int b0 = kc2 & 2;
#pragma unroll
        for (int u = 0; u < 2; u++) {
            int kc = kc2 + u;
#pragma unroll
            for (int j = 0; j < 4; j++)
                Ps[b0 + u][(rh + (l >> 4) * 4 + j) * 40 + kh + (l & 15)] = f2bf(s[kc][j]);
        }
        __syncthreads();
#pragma unroll
        for (int u = 0; u < 2; u++) {
            int kc = kc2 + u;
            bf8s pf = *(const bf8s*)&Ps[b0 + u][(rh + (l & 15)) * 40 + (l >> 4) * 8];
            bf8s vf = *(const bf8s*)(VTh + (size_t)(kh + (l & 15)) * 576 + kc * 32 + (l >> 4) * 8);
            oacc = mfma16(pf, vf, oacc);
        }
    }
#pragma unroll
    for (int j = 0; j < 4; j++) {
        float ov = oacc[j] * sm[j];
        size_t rowi = rowbase + n0 + rh + (l >> 4) * 4 + j;
        expand_cat1(ov, AX + rowi * 1792, h * 32 + kh + (l & 15));
    }
}

// ---------------- layernorm(sum of S bf16 partials) + residual (+opt next-layer expand) ----
__global__ __launch_bounds__(256) void k_ln_addS(const unsigned short* __restrict__ P,
                                                 int S, size_t st,
                                                 const float* __restrict__ SE,
                                                 const float* __restrict__ g,
                                                 const float* __restrict__ bb,
                                                 float* __restrict__ Out,
                                                 unsigned short* __restrict__ aexp,
                                                 int doExp) {
    int t = blockIdx.x, c = threadIdx.x;
    size_t o = (size_t)t * 256 + c;
    float v = 0.f;
    for (int s = 0; s < S; s++) v += bf2f(P[o + (size_t)s * st]);
    float s1 = v, s2 = v * v;
#pragma unroll
    for (int off = 32; off; off >>= 1) { s1 += __shfl_xor(s1, off); s2 += __shfl_xor(s2, off); }
    __shared__ float p1[4], p2[4];
    int wv_ = c >> 6, ln = c & 63;
    if (ln == 0) { p1[wv_] = s1; p2[wv_] = s2; }
    __syncthreads();
    s1 = p1[0] + p1[1] + p1[2] + p1[3];
    s2 = p2[0] + p2[1] + p2[2] + p2[3];
    float m = s1 * (1.f / 256.f);
    float var = s2 * (1.f / 256.f) - m * m;
    float y = (v - m) * rsqrtf(var + 1e-5f) * g[c] + bb[c];
    float xn = SE[o] + y;
    Out[o] = xn;
    if (doExp) expand_cat1(xn, aexp + (size_t)t * 1792, c);
}

__global__ __launch_bounds__(256) void k_ln_gelu(const float* __restrict__ Xin,
                                                 const float* __restrict__ g,
                                                 const float* __restrict__ bb,
                                                 float* __restrict__ Out) {
    int t = blockIdx.x, c = threadIdx.x;
    float v = Xin[t * 256 + c];
    float s1 = v, s2 = v * v;
#pragma unroll
    for (int off = 32; off; off >>= 1) { s1 += __shfl_xor(s1, off); s2 += __shfl_xor(s2, off); }
    __shared__ float p1[4], p2[4];
    int wv_ = c >> 6, ln = c & 63;
    if (ln == 0) { p1[wv_] = s1; p2[wv_] = s2; }
    __syncthreads();
    s1 = p1[0] + p1[1] + p1[2] + p1[3];
    s2 = p2[0] + p2[1] + p2[2] + p2[3];
    float m = s1 * (1.f / 256.f);
    float var = s2 * (1.f / 256.f) - m * m;
    float y = (v - m) * rsqrtf(var + 1e-5f) * g[c] + bb[c];
    Out[t * 256 + c] = gelu_f(y);
}

// ---------------- mean pool, BOTH streams in one launch ----------------
__global__ __launch_bounds__(256) void k_meanpool2(const float* __restrict__ X,
                                                   float* __restrict__ si) {
    int idx = blockIdx.x * 256 + threadIdx.x;
    if (idx >= 2 * BB * CDIM) return;
    int st = idx >= BB * CDIM;
    int off = idx - st * BB * CDIM;
    int b = off >> 8, c = off & 255;
    const float* Xs = X + (size_t)st * TT * 256;
    float s = 0.f;
    for (int n = 0; n < NTOK; n++) s += Xs[(size_t)(b * NTOK + n) * CDIM + c];
    si[b * 512 + st * 256 + c] = s * (1.f / 576.f);
}

// ---------------- head: KAN with inline bases expansion (+opt fusion-gate on input) ----
// Wb: (NN, K1) base weights. Ws: (NN, K1, 6) spline weights. gate: per-t scalar or null.
__global__ __launch_bounds__(64) void k_kan2(const float* __restrict__ A1, int K1,
                                             const float* __restrict__ Wb,
                                             const float* __restrict__ Ws,
                                             const float* __restrict__ gate,
                                             float* __restrict__ out, int NN, int act) {
    int o = blockIdx.x, t = blockIdx.y, ln = threadIdx.x;
    float s = 0.f;
    for (int k = ln; k < K1; k += 64) {
        float x = A1[t * K1 + k];
        if (gate) x *= (k < 256 ? gate[t] : 1.f - gate[t]);
        s += x * Wb[o * K1 + k];
        float b6[6]; bases6(x, b6);
        const float* wsp = Ws + ((size_t)o * K1 + k) * 6;
#pragma unroll
        for (int g = 0; g < 6; g++) s += b6[g] * wsp[g];
    }
#pragma unroll
    for (int off = 32; off; off >>= 1) s += __shfl_xor(s, off);
    if (ln == 0) {
        if (act == 1) s = gelu_f(s);
        else if (act == 2) s = 1.f / (1.f + __expf(-s));
        out[t * NN + o] = s;
    }
}

extern "C" void kernel_launch(void* const* d_in, const int* in_sizes, int n_in,
                              void* d_out, int out_size, void* d_ws, size_t ws_size,
                              hipStream_t stream) {
    (void)in_sizes; (void)n_in; (void)out_size;
    const float* sat_f = (const float*)d_in[0];
    const float* uav_f = (const float*)d_in[1];
    const float* s_qb  = (const float*)d_in[2];
    const float* s_qs  = (const float*)d_in[3];
    const float* s_rb  = (const float*)d_in[4];
    const float* s_rs  = (const float*)d_in[5];
    const float* u_qb  = (const float*)d_in[6];
    const float* u_qs  = (const float*)d_in[7];
    const float* u_rb  = (const float*)d_in[8];
    const float* u_rs  = (const float*)d_in[9];
    const float* r_w1b = (const float*)d_in[10];
    const float* r_w1s = (const float*)d_in[11];
    const float* r_w2b = (const float*)d_in[12];
    const float* r_w2s = (const float*)d_in[13];
    const float* r_lng = (const float*)d_in[14];
    const float* r_lnb = (const float*)d_in[15];
    const float* m_w1b = (const float*)d_in[16];
    const float* m_w1s = (const float*)d_in[17];
    const float* m_w2b = (const float*)d_in[18];
    const float* m_w2s = (const float*)d_in[19];
    const float* m_w3b = (const float*)d_in[20];
    const float* m_w3s = (const float*)d_in[21];
    const float* f_wb  = (const float*)d_in[22];
    const float* f_ws  = (const float*)d_in[23];
    const float* f_lng = (const float*)d_in[24];
    const float* f_lnb = (const float*)d_in[25];

    const size_t nQ = 1376256, nP = 458752;   // per-stream ushort counts (K=1792 layout)

    float* X; unsigned short* QKVb; unsigned short* VT; char* R; float* PS;
    unsigned short* AEXP;
    unsigned short *Wq, *Wp, *Ww1, *Ww2;
    float *Btab, *si, *SB, *h1f, *h2f, *wvv, *fiB, *ftmp;
    auto plan = [&](int nb, bool ded, bool pall, bool assign) -> size_t {
        size_t off = 0;
        auto take = [&](size_t bytes) -> char* {
            char* rp = (char*)d_ws + off;
            off = (off + bytes + 255) & ~(size_t)255;
            return rp;
        };
        size_t Mr = (size_t)nb * TT;
        int nl = pall ? 3 : 1;
        char* p;
        p = take((size_t)2 * TT * 256 * 4);             if (assign) X = (float*)p;
        p = take(Mr * 768 * 2);                         if (assign) QKVb = (unsigned short*)p;
        p = take(Mr * 256 * 2);                         if (assign) VT = (unsigned short*)p;
        p = take(Mr * 2048 * 2);                        if (assign) R = p;
        p = take((size_t)4 * Mr * 256 * 4);             if (assign) PS = (float*)p;
        if (ded) { p = take(Mr * 1792 * 2);             if (assign) AEXP = (unsigned short*)p; }
        else     { if (assign) AEXP = (unsigned short*)PS; }
        p = take((size_t)nl * 2 * nQ * 2);              if (assign) Wq = (unsigned short*)p;
        p = take((size_t)nl * 2 * nP * 2);              if (assign) Wp = (unsigned short*)p;
        p = take((size_t)nl * 1835008 * 2);             if (assign) Ww1 = (unsigned short*)p;
        p = take((size_t)nl * 2097152 * 2);             if (assign) Ww2 = (unsigned short*)p;
        p = take((size_t)nb * NHEADS * 2209 * 4);       if (assign) Btab = (float*)p;
        p = take(BB * 512 * 4);                         if (assign) si = (float*)p;
        p = take((size_t)BB * 1024 * 6 * 4);            if (assign) SB = (float*)p;
        p = take(BB * 1024 * 4);                        if (assign) h1f = (float*)p;
        p = take(BB * 64 * 4);                          if (assign) h2f = (float*)p;
        p = take(64 * 4);                               if (assign) wvv = (float*)p;
        p = take(BB * 512 * 4);                         if (assign) fiB = (float*)p;
        p = take(BB * 256 * 4);                         if (assign) ftmp = (float*)p;
        return off;
    };
    int nb; bool ded, pall;
    if      (ws_size >= plan(2, true,  true,  false)) { nb = 2; ded = true;  pall = true;  }
    else if (ws_size >= plan(2, true,  false, false)) { nb = 2; ded = true;  pall = false; }
    else if (ws_size >= plan(2, false, false, false)) { nb = 2; ded = false; pall = false; }
    else                                              { nb = 1; ded = true;  pall = false; }
    plan(nb, ded, pall, true);
    (void)Btab; (void)SB; (void)fiB;   // bias/bases now computed in-kernel; gate inline
    const bool fuseRed = ded;
    const bool fuseLn  = ded && (nb == 2);

    // transpose both streams; when fuseLn (AEXP dedicated + single 2-stream batch),
    // also emit the l=0 QKV expansion directly (skips k_expand8 entirely)
    k_transpose2<<<2 * TT, 256, 0, stream>>>(sat_f, uav_f, X, AEXP, fuseLn ? 1 : 0);

    const int Mr = nb * TT;
    const size_t pStride = (size_t)Mr * 256;
    unsigned short* AEXPp = (unsigned short*)R;    // attn-expanded proj input (K=1792 rows)
    unsigned short* H1bp  = (unsigned short*)R;
    float* SEbp = (float*)(R + (size_t)Mr * 1024 * 2);

    if (pall)
        k_pack8<<<dim3(6400, 3), 256, 0, stream>>>(s_qb, s_qs, u_qb, u_qs,
                                                   r_w1b, r_w1s, r_w2b, r_w2s,
                                                   Wq, Wp, Ww1, Ww2);

    for (int l = 0; l < 3; l++) {
        if (!pall)
            k_pack8<<<dim3(6400, 1), 256, 0, stream>>>(
                s_qb + (size_t)l * 262144, s_qs + (size_t)l * 1572864,
                u_qb + (size_t)l * 262144, u_qs + (size_t)l * 1572864,
                r_w1b + (size_t)l * 262144, r_w1s + (size_t)l * 1572864,
                r_w2b + (size_t)l * 262144, r_w2s + (size_t)l * 1572864,
                Wq, Wp, Ww1, Ww2);
        unsigned short* WqL  = Wq  + (pall ? (size_t)l * 2 * nQ : 0);
        unsigned short* WpL  = Wp  + (pall ? (size_t)l * 2 * nP : 0);
        unsigned short* Ww1L = Ww1 + (pall ? (size_t)l * 1835008 : 0);
        unsigned short* Ww2L = Ww2 + (pall ? (size_t)l * 2097152 : 0);

        for (int st0 = 0; st0 < 2; st0 += nb) {
            float* Xs = X + (size_t)st0 * TT * 256;
            const float* rbA = (st0 ? u_rb : s_rb) + l * 16;
            const float* rsA = (st0 ? u_rs : s_rs) + l * 96;
            // QKV: A = concatenated expanded X (K=1792); AEXP pre-filled by
            // transpose (l=0, fuseLn) or previous ln_addS (l>0, fuseLn)
            bool haveAexp = fuseLn;
            if (!haveAexp) k_expand8<<<Mr / 4, 256, 0, stream>>>(Xs, AEXP, Mr);
            mgemm<128, 128, 0, 2, 0><<<6 * (Mr / 128), 256, 0, stream>>>(
                AEXP, WqL + (size_t)st0 * nQ, WqL + nQ, (void*)QKVb,
                768, 1792, 1792, 1792, 6, TT, 1, 1792, 0);
            // V transpose + attention (bias computed in-kernel; writes concatenated proj-A)
            k_vt<<<dim3(9, 8, nb * 8), 256, 0, stream>>>(QKVb, VT);
            k_attn2<<<144 * nb * 8, 256, 0, stream>>>(QKVb, VT, rbA, rsA,
                                                      u_rb + l * 16, u_rs + l * 96, AEXPp);
            // proj: pure gload GEMM (K=1792), split-K S=4, bf16 partials; reduce (+w1 expand)
            mgemm<128, 128, 0, 5, 0><<<2 * (Mr / 128) * 4, 256, 0, stream>>>(
                AEXPp, WpL + (size_t)st0 * nP, WpL + nP, (void*)PS,
                256, 1792, 1792, 1792, 2, TT, 4, 448, pStride);
            if (fuseRed)
                k_reduce_exp<<<Mr / 4, 256, 0, stream>>>((const unsigned short*)PS, (float4*)SEbp, AEXP, Mr * 64, 4);
            else {
                k_reduceS<<<Mr / 4, 256, 0, stream>>>((const unsigned short*)PS, (float4*)SEbp, Mr * 64, 4);
                k_expand8<<<Mr / 4, 256, 0, stream>>>(SEbp, AEXP, Mr);
            }
            // refine w1: pure gload GEMM (K=1792, +gelu, bf16 out)
            mgemm<128, 128, 1, 2, 0><<<8 * (Mr / 128), 256, 0, stream>>>(
                AEXP, Ww1L, Ww1L, (void*)H1bp,
                1024, 1792, 1792, 1792, 8, TT, 1, 1792, 0);
            // refine w2: fused expand (groups-of-8 K=8192), BM=64 BN=256 gx=1, S=4,
            // bf16 partials -- best-known config
            mgemm<64, 256, 0, 5, 2><<<4 * (Mr / 64), 256, 0, stream>>>(
                H1bp, Ww2L, Ww2L, (void*)PS,
                256, 8192, 1024, 8192, 1, TT, 4, 2048, pStride);
            // LN(sum of 4 bf16 partials) + residual -> X (+next-layer QKV expand when fused)
            k_ln_addS<<<Mr, 256, 0, stream>>>((const unsigned short*)PS, 4, pStride, SEbp,
                                              r_lng + l * 256, r_lnb + l * 256, Xs,
                                              AEXP, (fuseLn && l < 2) ? 1 : 0);
        }
    }

    // final head (fp32, tiny; inline bases expansion + inline fusion gate)
    k_meanpool2<<<16, 256, 0, stream>>>(X, si);
    k_kan2<<<dim3(1024, BB), 64, 0, stream>>>(si, 512, m_w1b, m_w1s, nullptr, h1f, 1024, 1);
    k_kan2<<<dim3(64, BB), 64, 0, stream>>>(h1f, 1024, m_w2b, m_w2s, nullptr, h2f, 64, 1);
    k_kan2<<<dim3(1, BB), 64, 0, stream>>>(h2f, 64, m_w3b, m_w3s, nullptr, wvv, 1, 2);
    k_kan2<<<dim3(256, BB), 64, 0, stream>>>(si, 512, f_wb, f_ws, wvv, ftmp, 256, 0);
    k_ln_gelu<<<8, 256, 0, stream>>>(ftmp, f_lng, f_lnb, (float*)d_out);
}